// Round 1
// baseline (27.182 us; speedup 1.0000x reference)
//
#include <hip/hip_runtime.h>

// YOLO head decode: x [bs, nm*attrs, H, W] fp32, anchors [nm,2] fp32
// out = concat(pred [bs,nm,H,W,7], valid [bs,nm,H,W]) fp32 (valid as 0/1)

#define BS    16
#define NM    3
#define NC    80
#define ATTRS (5 + NC)
#define HH    76
#define WW    76
#define HWSZ  (HH * WW)
#define VAL_CONF 0.1f

typedef float f4 __attribute__((ext_vector_type(4)));

__device__ __forceinline__ float sigmoidf(float v) {
    return 1.0f / (1.0f + __expf(-v));
}

__global__ __launch_bounds__(256) void yolo_head_kernel(
    const float* __restrict__ x,
    const float* __restrict__ anchors,
    float* __restrict__ out) {

    const int total4 = BS * NM * HWSZ / 4;
    const int tid = blockIdx.x * blockDim.x + threadIdx.x;
    if (tid >= total4) return;

    const int e0  = tid * 4;          // first linear (b,m,h,w) index of this thread
    const int bm  = e0 / HWSZ;        // HWSZ % 4 == 0 -> all 4 elems share bm
    const int hw0 = e0 - bm * HWSZ;
    const int m   = bm % NM;

    const float aw = anchors[2 * m + 0];
    const float ah = anchors[2 * m + 1];

    const float* base = x + (size_t)bm * ATTRS * HWSZ + hw0;

    // attribute planes 0..4: tx, ty, tw, th, conf (raw)
    f4 tx = *(const f4*)(base + 0 * HWSZ);
    f4 ty = *(const f4*)(base + 1 * HWSZ);
    f4 tw = *(const f4*)(base + 2 * HWSZ);
    f4 th = *(const f4*)(base + 3 * HWSZ);
    f4 tc = *(const f4*)(base + 4 * HWSZ);

    // class max / argmax over RAW logits (sigmoid is monotonic)
    f4 mx = *(const f4*)(base + 5 * HWSZ);
    int mi[4] = {0, 0, 0, 0};
    for (int k = 1; k < NC; ++k) {
        f4 c = *(const f4*)(base + (size_t)(5 + k) * HWSZ);
        #pragma unroll
        for (int j = 0; j < 4; ++j) {
            if (c[j] > mx[j]) { mx[j] = c[j]; mi[j] = k; }
        }
    }

    float* pred  = out;
    float* valid = out + (size_t)BS * NM * HWSZ * 7;

    float o[28];
    f4 vmask;

    #pragma unroll
    for (int j = 0; j < 4; ++j) {
        const int hw = hw0 + j;
        const int h  = hw / WW;
        const int w  = hw - h * WW;

        const float sx = sigmoidf(tx[j]);
        const float sy = sigmoidf(ty[j]);
        const float cx = (sx + (float)w) * (1.0f / (float)WW);
        const float cy = (sy + (float)h) * (1.0f / (float)HH);
        const float bw = __expf(tw[j]) * aw;
        const float bh = __expf(th[j]) * ah;
        const float conf = sigmoidf(tc[j]);
        const float cls_score = sigmoidf(mx[j]);
        const float cls_idx = (float)mi[j];

        const float fm = (conf > VAL_CONF) ? 1.0f : 0.0f;
        vmask[j] = fm;

        o[j * 7 + 0] = (cx - bw * 0.5f) * fm;
        o[j * 7 + 1] = (cy - bh * 0.5f) * fm;
        o[j * 7 + 2] = (cx + bw * 0.5f) * fm;
        o[j * 7 + 3] = (cy + bh * 0.5f) * fm;
        o[j * 7 + 4] = conf * fm;
        o[j * 7 + 5] = cls_score * fm;
        o[j * 7 + 6] = cls_idx * fm;
    }

    // 28 contiguous floats at pred + 28*tid; 112*tid bytes -> 16B aligned
    f4* pdst = (f4*)(pred + (size_t)e0 * 7);
    #pragma unroll
    for (int q = 0; q < 7; ++q) {
        pdst[q] = *(const f4*)(&o[q * 4]);
    }
    *(f4*)(valid + e0) = vmask;
}

extern "C" void kernel_launch(void* const* d_in, const int* in_sizes, int n_in,
                              void* d_out, int out_size, void* d_ws, size_t ws_size,
                              hipStream_t stream) {
    const float* x       = (const float*)d_in[0];
    const float* anchors = (const float*)d_in[1];
    float* out           = (float*)d_out;

    const int total4 = BS * NM * HWSZ / 4;   // 69312 threads
    const int block  = 256;
    const int grid   = (total4 + block - 1) / block;

    yolo_head_kernel<<<grid, block, 0, stream>>>(x, anchors, out);
}

// Round 2
// 21.954 us; speedup vs baseline: 1.2382x; 1.2382x over previous
//
#include <hip/hip_runtime.h>

// YOLO head decode: x [bs, nm*attrs, H, W] fp32, anchors [nm,2] fp32
// out = concat(pred [bs,nm,H,W,7], valid [bs,nm,H,W]) fp32 (valid as 0/1)
//
// R2: one spatial location per thread (277,248 threads = 4332 waves,
// ~17 waves/CU) instead of four (1083 waves, ~1 wave/SIMD). Memory-bound
// kernel needs TLP to hide ~900cy HBM latency; R1's grid was 4x too small
// and had a 271-block tail imbalance. Grid is exactly 1083 x 256.

#define BS    16
#define NM    3
#define NC    80
#define ATTRS (5 + NC)
#define HH    76
#define WW    76
#define HWSZ  (HH * WW)
#define VAL_CONF 0.1f

__device__ __forceinline__ float sigmoidf(float v) {
    return 1.0f / (1.0f + __expf(-v));
}

__global__ __launch_bounds__(256) void yolo_head_kernel(
    const float* __restrict__ x,
    const float* __restrict__ anchors,
    float* __restrict__ out) {

    const int tid = blockIdx.x * blockDim.x + threadIdx.x;   // elem in [0, BS*NM*HWSZ)

    const int bm = tid / HWSZ;          // (batch, mask) plane group
    const int hw = tid - bm * HWSZ;
    const int m  = bm % NM;

    const float aw = anchors[2 * m + 0];
    const float ah = anchors[2 * m + 1];

    const float* base = x + (size_t)bm * ATTRS * HWSZ + hw;

    const float tx = base[0 * HWSZ];
    const float ty = base[1 * HWSZ];
    const float tw = base[2 * HWSZ];
    const float th = base[3 * HWSZ];
    const float tc = base[4 * HWSZ];

    // class max / argmax over RAW logits (sigmoid is monotonic);
    // strict > keeps first-max index, matching jnp.argmax.
    float mx = base[5 * HWSZ];
    int   mi = 0;
    #pragma unroll
    for (int k = 1; k < NC; ++k) {
        const float c = base[(size_t)(5 + k) * HWSZ];
        if (c > mx) { mx = c; mi = k; }
    }

    const int h = hw / WW;
    const int w = hw - h * WW;

    const float sx = sigmoidf(tx);
    const float sy = sigmoidf(ty);
    const float cx = (sx + (float)w) * (1.0f / (float)WW);
    const float cy = (sy + (float)h) * (1.0f / (float)HH);
    const float bw = __expf(tw) * aw;
    const float bh = __expf(th) * ah;
    const float conf      = sigmoidf(tc);
    const float cls_score = sigmoidf(mx);
    const float cls_idx   = (float)mi;

    const float fm = (conf > VAL_CONF) ? 1.0f : 0.0f;

    float* pred = out + (size_t)tid * 7;
    pred[0] = (cx - bw * 0.5f) * fm;
    pred[1] = (cy - bh * 0.5f) * fm;
    pred[2] = (cx + bw * 0.5f) * fm;
    pred[3] = (cy + bh * 0.5f) * fm;
    pred[4] = conf * fm;
    pred[5] = cls_score * fm;
    pred[6] = cls_idx * fm;

    out[(size_t)BS * NM * HWSZ * 7 + tid] = fm;
}

extern "C" void kernel_launch(void* const* d_in, const int* in_sizes, int n_in,
                              void* d_out, int out_size, void* d_ws, size_t ws_size,
                              hipStream_t stream) {
    const float* x       = (const float*)d_in[0];
    const float* anchors = (const float*)d_in[1];
    float* out           = (float*)d_out;

    const int total = BS * NM * HWSZ;        // 277,248
    const int block = 256;
    const int grid  = total / block;         // 1083 exactly

    yolo_head_kernel<<<grid, block, 0, stream>>>(x, anchors, out);
}